// Round 1
// baseline (171.367 us; speedup 1.0000x reference)
//
#include <hip/hip_runtime.h>

// VP_lattice reverse step, B = 2^20 rows. Round-4:
//  - R3 math kept verbatim (trig eigenvalues + Hoger-Carlson sqrtm, LDS
//    schedule tables).
//  - NEW: all bulk global traffic (plat 36B/row, lt/pl0/zn 24B/row, out)
//    restructured to fully-coalesced float4 via LDS tiles. R3 did per-lane
//    AoS strided access (9x dword @ stride 36 + 9x float2 @ stride 24 +
//    3x float2 stores) = ~4.5x TA/L1 transaction amplification — the
//    theory for why R3 sat at ~0.9 TB/s (14% of achievable HBM).
//  - LDS: 12KB sched + 9KB plat tile (reused for out) + 3x6KB input tiles
//    = 38.7KB -> 4 blocks/CU (16 waves/CU), fine for coalesced streaming.
//  - plat LDS reads stride 9 (odd) = bank-conflict-free; 6-float tiles
//    read as float2 (4-way conflict on 32 banks, ~1.58x on cheap ds_reads).

#define NUM_STEPS 1000
#define BLOCK 256

__global__ __launch_bounds__(BLOCK) void vp_lattice_kernel(
    const float* __restrict__ lt,
    const float* __restrict__ pl0,
    const float* __restrict__ plat,
    const float* __restrict__ alpha_bars,
    const float* __restrict__ betas,
    const float* __restrict__ sigmas,
    const float* __restrict__ z_noise,
    const int*   __restrict__ t,
    float* __restrict__ out,
    int n)
{
    // ---- LDS: schedule tables + streaming tiles ----
    __shared__ float sCoef[NUM_STEPS + 1];
    __shared__ float sScale[NUM_STEPS + 1];
    __shared__ float sSig[NUM_STEPS + 1];
    __shared__ __align__(16) float platT[BLOCK * 9];  // 9216 B; reused as out tile
    __shared__ __align__(16) float ltT[BLOCK * 6];    // 6144 B
    __shared__ __align__(16) float p0T[BLOCK * 6];
    __shared__ __align__(16) float znT[BLOCK * 6];

    const int tid = threadIdx.x;
    const int rowBase = blockIdx.x * BLOCK;
    int rem = n - rowBase; if (rem > BLOCK) rem = BLOCK;

    // ---- stage input tiles: fully-coalesced float4 (16B/lane) ----
    if (rem == BLOCK) {
        const float4* g9 = reinterpret_cast<const float4*>(plat + (size_t)rowBase * 9);
        float4*       s9 = reinterpret_cast<float4*>(platT);
        for (int j = tid; j < BLOCK * 9 / 4; j += BLOCK) s9[j] = g9[j];   // 576

        const float4* gl = reinterpret_cast<const float4*>(lt + (size_t)rowBase * 6);
        float4*       sl = reinterpret_cast<float4*>(ltT);
        for (int j = tid; j < BLOCK * 6 / 4; j += BLOCK) sl[j] = gl[j];   // 384

        const float4* gp = reinterpret_cast<const float4*>(pl0 + (size_t)rowBase * 6);
        float4*       sp = reinterpret_cast<float4*>(p0T);
        for (int j = tid; j < BLOCK * 6 / 4; j += BLOCK) sp[j] = gp[j];

        const float4* gz = reinterpret_cast<const float4*>(z_noise + (size_t)rowBase * 6);
        float4*       sz = reinterpret_cast<float4*>(znT);
        for (int j = tid; j < BLOCK * 6 / 4; j += BLOCK) sz[j] = gz[j];
    } else {
        // tail block (not hit at B=2^20, kept for generality): scalar staging
        for (int j = tid; j < rem * 9; j += BLOCK) platT[j] = plat[(size_t)rowBase * 9 + j];
        for (int j = tid; j < rem * 6; j += BLOCK) {
            ltT[j] = lt[(size_t)rowBase * 6 + j];
            p0T[j] = pl0[(size_t)rowBase * 6 + j];
            znT[j] = z_noise[(size_t)rowBase * 6 + j];
        }
    }

    // ---- schedule tables: coef, scale, sig*gate per timestep ----
    {
        float beta_last = betas[NUM_STEPS - 1];          // betas[-2]
        for (int j = tid; j <= NUM_STEPS; j += BLOCK) {
            float alpha = 1.0f - fminf(betas[j], beta_last);
            sCoef[j]  = 1.0f / sqrtf(alpha + 1e-8f);
            sScale[j] = (1.0f - alpha) / sqrtf(1.0f - alpha_bars[j] + 1e-8f);
            sSig[j]   = (j > 1) ? sigmas[j] : 0.0f;
        }
    }

    // coalesced t gather, issued before the barrier to overlap latency
    int ti = (tid < rem) ? t[rowBase + tid] : 0;

    __syncthreads();

    float ov0 = 0.f, ov1 = 0.f, ov2 = 0.f, ov3 = 0.f, ov4 = 0.f, ov5 = 0.f;

    if (tid < rem) {
        // ---- load A (3x3 row-major) from LDS; stride 9 = conflict-free ----
        const float* pr = platT + tid * 9;
        float a00 = pr[0], a01 = pr[1], a02 = pr[2];
        float a10 = pr[3], a11 = pr[4], a12 = pr[5];
        float a20 = pr[6], a21 = pr[7], a22 = pr[8];

        // ---- M = A^T A (symmetric PSD) ----
        float m00 = a00*a00 + a10*a10 + a20*a20;
        float m01 = a00*a01 + a10*a11 + a20*a21;
        float m02 = a00*a02 + a10*a12 + a20*a22;
        float m11 = a01*a01 + a11*a11 + a21*a21;
        float m12 = a01*a02 + a11*a12 + a21*a22;
        float m22 = a02*a02 + a12*a12 + a22*a22;

        // ---- eigenvalues: cancellation-free trig form ----
        float q  = (m00 + m11 + m22) * (1.0f/3.0f);
        float b00 = m00 - q, b11 = m11 - q, b22 = m22 - q;
        float p1 = m01*m01 + m02*m02 + m12*m12;
        float p2 = b00*b00 + b11*b11 + b22*b22 + 2.0f*p1;
        float p  = sqrtf(p2 * (1.0f/6.0f));
        float detB = b00*(b11*b22 - m12*m12)
                   - m01*(m01*b22 - m12*m02)
                   + m02*(m01*m12 - b11*m02);
        float pinv = 1.0f / fmaxf(p, 1e-20f);
        float r = 0.5f * detB * pinv * pinv * pinv;
        r = fminf(fmaxf(r, -1.0f), 1.0f);
        float phi = acosf(r) * (1.0f/3.0f);                  // [0, pi/3]
        float mu1 = q + 2.0f*p*cosf(phi);                    // largest
        float mu3 = q + 2.0f*p*cosf(phi + 2.0943951023931953f); // smallest
        float mu2 = 3.0f*q - mu1 - mu3;
        float l1 = sqrtf(fmaxf(mu1, 0.0f));
        float l2 = sqrtf(fmaxf(mu2, 0.0f));
        float l3 = sqrtf(fmaxf(mu3, 0.0f));

        // ---- U = sqrtm(M), Hoger-Carlson (inverse-free) ----
        float IU   = l1 + l2 + l3;
        float IIU  = l1*(l2 + l3) + l2*l3;
        float IIIU = l1*l2*l3;
        float denom = (l1 + l2) * (l1 + l3) * (l2 + l3);
        float dinv  = 1.0f / fmaxf(denom, 1e-25f);
        float sd = (IU*IU - IIU) * dinv;      // coefficient of M
        float td = IU * IIIU * dinv;          // coefficient of Id
        float nd = -dinv;                     // coefficient of M^2

        float mm00 = m00*m00 + m01*m01 + m02*m02;
        float mm01 = m00*m01 + m01*m11 + m02*m12;
        float mm02 = m00*m02 + m01*m12 + m02*m22;
        float mm11 = m01*m01 + m11*m11 + m12*m12;
        float mm12 = m01*m02 + m11*m12 + m12*m22;
        float mm22 = m02*m02 + m12*m12 + m22*m22;

        float v0 = nd*mm00 + sd*m00 + td;     // L00
        float v1 = nd*mm01 + sd*m01;          // L01
        float v2 = nd*mm02 + sd*m02;          // L02
        float v3 = nd*mm11 + sd*m11 + td;     // L11
        float v4 = nd*mm12 + sd*m12;          // L12
        float v5 = nd*mm22 + sd*m22 + td;     // L22

        // ---- schedule from LDS ----
        float coef  = sCoef[ti];
        float scale = sScale[ti];
        float sig   = sSig[ti];

        // ---- epilogue inputs from LDS (float2) ----
        const float2* l2v = reinterpret_cast<const float2*>(ltT) + tid * 3;
        const float2* p2v = reinterpret_cast<const float2*>(p0T) + tid * 3;
        const float2* z2v = reinterpret_cast<const float2*>(znT) + tid * 3;
        float lv[6], pv[6], zv[6];
        float2 w;
        w = l2v[0]; lv[0]=w.x; lv[1]=w.y;
        w = l2v[1]; lv[2]=w.x; lv[3]=w.y;
        w = l2v[2]; lv[4]=w.x; lv[5]=w.y;
        w = p2v[0]; pv[0]=w.x; pv[1]=w.y;
        w = p2v[1]; pv[2]=w.x; pv[3]=w.y;
        w = p2v[2]; pv[4]=w.x; pv[5]=w.y;
        w = z2v[0]; zv[0]=w.x; zv[1]=w.y;
        w = z2v[1]; zv[2]=w.x; zv[3]=w.y;
        w = z2v[2]; zv[4]=w.x; zv[5]=w.y;

        float vv[6] = {v0, v1, v2, v3, v4, v5};
        float ovv[6];
#pragma unroll
        for (int c = 0; c < 6; ++c) {
            float lc = lv[c];
            float pn = lc - 0.5f * (vv[c] + pv[c]);          // predicted_noise
            ovv[c] = coef * (lc - scale * pn) + sig * zv[c];
        }
        ov0 = ovv[0]; ov1 = ovv[1]; ov2 = ovv[2];
        ov3 = ovv[3]; ov4 = ovv[4]; ov5 = ovv[5];
    }

    // all platT reads are done -> reuse it as the out tile
    __syncthreads();

    if (tid < rem) {
        float2* o2 = reinterpret_cast<float2*>(platT) + tid * 3;
        o2[0] = make_float2(ov0, ov1);
        o2[1] = make_float2(ov2, ov3);
        o2[2] = make_float2(ov4, ov5);
    }

    __syncthreads();

    // ---- coalesced float4 store ----
    if (rem == BLOCK) {
        const float4* so = reinterpret_cast<const float4*>(platT);
        float4*       go = reinterpret_cast<float4*>(out + (size_t)rowBase * 6);
        for (int j = tid; j < BLOCK * 6 / 4; j += BLOCK) go[j] = so[j];
    } else {
        for (int j = tid; j < rem * 6; j += BLOCK) out[(size_t)rowBase * 6 + j] = platT[j];
    }
}

extern "C" void kernel_launch(void* const* d_in, const int* in_sizes, int n_in,
                              void* d_out, int out_size, void* d_ws, size_t ws_size,
                              hipStream_t stream) {
    const float* lt         = (const float*)d_in[0];
    const float* pl0        = (const float*)d_in[1];
    const float* plat       = (const float*)d_in[2];
    const float* alpha_bars = (const float*)d_in[3];
    const float* betas      = (const float*)d_in[4];
    const float* sigmas     = (const float*)d_in[5];
    const float* z_noise    = (const float*)d_in[6];
    const int*   t          = (const int*)d_in[7];
    float* out = (float*)d_out;

    int n = in_sizes[0] / 6;   // B rows
    int grid = (n + BLOCK - 1) / BLOCK;
    vp_lattice_kernel<<<grid, BLOCK, 0, stream>>>(
        lt, pl0, plat, alpha_bars, betas, sigmas, z_noise, t, out, n);
}

// Round 2
// 154.770 us; speedup vs baseline: 1.1072x; 1.1072x over previous
//
#include <hip/hip_runtime.h>

// VP_lattice reverse step, B = 2^20 rows. Round-5:
//  Evidence from R4 counters: dur 62us, HBM 17%, VALU 28%, Occ 37.5% ->
//  latency/occupancy-bound, NOT bandwidth-bound. Full-tile LDS staging
//  (39.9KB -> 4 blocks/CU) + 3 barriers over-serialized the block.
//  - Stage ONLY plat via LDS (36B-stride = 9x TA amplification if direct;
//    lt/pl0/zn at 24B stride are L1-absorbed as direct float2). LDS
//    21.3KB -> 7 blocks/CU, ONE barrier per block.
//  - Schedule table hoisted to a pre-kernel into d_ws (4096x redundant
//    per-block recompute -> 1x); main blocks copy 3 float4/thread.
//    Folded coefficients: out = A*lt + B*(vec+pl0) + S*z.
//    Fallback to in-block compute if ws_size insufficient.
//  - ocml acosf/cosf -> Hastings poly (|err|<=7e-5 rad; absmax budget
//    7.8e-3) + native __cosf; __fdividef for reciprocals. ~150 fewer
//    VALU/thread.

#define NUM_STEPS 1000
#define TBL 1008          // 1001 rounded up to x16 floats for float4 copies
#define BLOCK 256

// ---------------- schedule pre-kernel (runs once, ~2us) ----------------
__global__ __launch_bounds__(256) void sched_kernel(
    const float* __restrict__ alpha_bars,
    const float* __restrict__ betas,
    const float* __restrict__ sigmas,
    float* __restrict__ ws)          // layout: [A[TBL] | B[TBL] | S[TBL]]
{
    int j = blockIdx.x * blockDim.x + threadIdx.x;
    if (j >= TBL) return;
    if (j <= NUM_STEPS) {
        float beta_last = betas[NUM_STEPS - 1];              // betas[-2]
        float alpha = 1.0f - fminf(betas[j], beta_last);     // clamp_min
        float coef  = 1.0f / sqrtf(alpha + 1e-8f);
        float scale = (1.0f - alpha) / sqrtf(1.0f - alpha_bars[j] + 1e-8f);
        ws[j]           = coef * (1.0f - scale);             // A
        ws[TBL + j]     = 0.5f * coef * scale;               // B
        ws[2 * TBL + j] = (j > 1) ? sigmas[j] : 0.0f;        // S (z-gated)
    } else {
        ws[j] = 0.0f; ws[TBL + j] = 0.0f; ws[2 * TBL + j] = 0.0f;
    }
}

// ---------------- main kernel ----------------
__global__ __launch_bounds__(BLOCK, 6) void vp_lattice_kernel(
    const float* __restrict__ lt,
    const float* __restrict__ pl0,
    const float* __restrict__ plat,
    const float* __restrict__ alpha_bars,
    const float* __restrict__ betas,
    const float* __restrict__ sigmas,
    const float* __restrict__ z_noise,
    const int*   __restrict__ t,
    float* __restrict__ out,
    int n,
    const float* __restrict__ ws,
    int use_ws)
{
    __shared__ __align__(16) float sA[TBL];
    __shared__ __align__(16) float sB[TBL];
    __shared__ __align__(16) float sS[TBL];
    __shared__ __align__(16) float platT[BLOCK * 9];   // 9216 B

    const int tid = threadIdx.x;
    const int rowBase = blockIdx.x * BLOCK;
    int rem = n - rowBase; if (rem > BLOCK) rem = BLOCK;

    // ---- stage plat tile: coalesced float4 (the only 16B-unalignable array) ----
    if (rem == BLOCK) {
        const float4* g9 = reinterpret_cast<const float4*>(plat + (size_t)rowBase * 9);
        float4*       s9 = reinterpret_cast<float4*>(platT);
#pragma unroll
        for (int k = 0; k < 3; ++k) {                 // 576 float4 / 256 threads
            int j = tid + k * BLOCK;
            if (j < BLOCK * 9 / 4) s9[j] = g9[j];
        }
    } else {
        for (int j = tid; j < rem * 9; j += BLOCK)
            platT[j] = plat[(size_t)rowBase * 9 + j];
    }

    // ---- schedule tables into LDS ----
    if (use_ws) {
        const float4* w4 = reinterpret_cast<const float4*>(ws);
        float4* a4 = reinterpret_cast<float4*>(sA);
        float4* b4 = reinterpret_cast<float4*>(sB);
        float4* s4 = reinterpret_cast<float4*>(sS);
        for (int j = tid; j < TBL / 4; j += BLOCK) {  // 252 -> 1 iter/thread
            a4[j] = w4[j];
            b4[j] = w4[TBL / 4 + j];
            s4[j] = w4[2 * (TBL / 4) + j];
        }
    } else {
        float beta_last = betas[NUM_STEPS - 1];
        for (int j = tid; j < TBL; j += BLOCK) {
            float A = 0.0f, Bc = 0.0f, S = 0.0f;
            if (j <= NUM_STEPS) {
                float alpha = 1.0f - fminf(betas[j], beta_last);
                float coef  = 1.0f / sqrtf(alpha + 1e-8f);
                float scale = (1.0f - alpha) / sqrtf(1.0f - alpha_bars[j] + 1e-8f);
                A  = coef * (1.0f - scale);
                Bc = 0.5f * coef * scale;
                S  = (j > 1) ? sigmas[j] : 0.0f;
            }
            sA[j] = A; sB[j] = Bc; sS[j] = S;
        }
    }

    // coalesced t gather before the barrier (latency overlap)
    int ti = (tid < rem) ? t[rowBase + tid] : 0;

    __syncthreads();   // the ONE barrier

    if (tid >= rem) return;

    // ---- epilogue inputs: direct float2 (8B-aligned rows), issued early ----
    size_t b6 = (size_t)(rowBase + tid) * 6;
    const float2* lt2 = reinterpret_cast<const float2*>(lt + b6);
    const float2* p02 = reinterpret_cast<const float2*>(pl0 + b6);
    const float2* zn2 = reinterpret_cast<const float2*>(z_noise + b6);
    float2 lw0 = lt2[0], lw1 = lt2[1], lw2 = lt2[2];
    float2 pw0 = p02[0], pw1 = p02[1], pw2 = p02[2];
    float2 zw0 = zn2[0], zw1 = zn2[1], zw2 = zn2[2];

    // ---- load A (3x3) from LDS; stride 9 (odd) = bank-conflict-free ----
    const float* pr = platT + tid * 9;
    float a00 = pr[0], a01 = pr[1], a02 = pr[2];
    float a10 = pr[3], a11 = pr[4], a12 = pr[5];
    float a20 = pr[6], a21 = pr[7], a22 = pr[8];

    // ---- M = A^T A (symmetric PSD) ----
    float m00 = a00*a00 + a10*a10 + a20*a20;
    float m01 = a00*a01 + a10*a11 + a20*a21;
    float m02 = a00*a02 + a10*a12 + a20*a22;
    float m11 = a01*a01 + a11*a11 + a21*a21;
    float m12 = a01*a02 + a11*a12 + a21*a22;
    float m22 = a02*a02 + a12*a12 + a22*a22;

    // ---- eigenvalues: cancellation-free trig form ----
    float q  = (m00 + m11 + m22) * (1.0f/3.0f);
    float b00 = m00 - q, b11 = m11 - q, b22 = m22 - q;
    float p1 = m01*m01 + m02*m02 + m12*m12;
    float p2 = b00*b00 + b11*b11 + b22*b22 + 2.0f*p1;
    float p  = sqrtf(p2 * (1.0f/6.0f));
    float detB = b00*(b11*b22 - m12*m12)
               - m01*(m01*b22 - m12*m02)
               + m02*(m01*m12 - b11*m02);
    float pinv = __fdividef(1.0f, fmaxf(p, 1e-20f));
    float r = 0.5f * detB * pinv * pinv * pinv;
    r = fminf(fmaxf(r, -1.0f), 1.0f);

    // acos via Hastings poly (AS 4.4.45, |err|<=6.8e-5 rad), then native cos
    float ar = fabsf(r);
    float sq = sqrtf(1.0f - ar);
    float pl = 1.5707288f + ar * (-0.2121144f + ar * (0.0742610f - ar * 0.0187293f));
    float ac = sq * pl;
    float acr = (r >= 0.0f) ? ac : (3.14159265358979f - ac);
    float phi = acr * (1.0f/3.0f);                           // [0, pi/3]
    float mu1 = q + 2.0f*p*__cosf(phi);                      // largest
    float mu3 = q + 2.0f*p*__cosf(phi + 2.0943951023931953f);// smallest
    float mu2 = 3.0f*q - mu1 - mu3;
    float l1 = sqrtf(fmaxf(mu1, 0.0f));
    float l2 = sqrtf(fmaxf(mu2, 0.0f));
    float l3 = sqrtf(fmaxf(mu3, 0.0f));

    // ---- U = sqrtm(M), Hoger-Carlson (inverse-free) ----
    float IU   = l1 + l2 + l3;
    float IIU  = l1*(l2 + l3) + l2*l3;
    float IIIU = l1*l2*l3;
    float denom = (l1 + l2) * (l1 + l3) * (l2 + l3);
    float dinv  = __fdividef(1.0f, fmaxf(denom, 1e-25f));
    float sd = (IU*IU - IIU) * dinv;      // coefficient of M
    float td = IU * IIIU * dinv;          // coefficient of Id
    float nd = -dinv;                     // coefficient of M^2

    float mm00 = m00*m00 + m01*m01 + m02*m02;
    float mm01 = m00*m01 + m01*m11 + m02*m12;
    float mm02 = m00*m02 + m01*m12 + m02*m22;
    float mm11 = m01*m01 + m11*m11 + m12*m12;
    float mm12 = m01*m02 + m11*m12 + m12*m22;
    float mm22 = m02*m02 + m12*m12 + m22*m22;

    float v0 = nd*mm00 + sd*m00 + td;     // L00
    float v1 = nd*mm01 + sd*m01;          // L01
    float v2 = nd*mm02 + sd*m02;          // L02
    float v3 = nd*mm11 + sd*m11 + td;     // L11
    float v4 = nd*mm12 + sd*m12;          // L12
    float v5 = nd*mm22 + sd*m22 + td;     // L22

    // ---- schedule coefficients from LDS (3 gathers) ----
    float A  = sA[ti];
    float Bc = sB[ti];
    float S  = sS[ti];

    // ---- epilogue: out = A*lt + B*(vec + pl0) + S*z ----
    float2 o0, o1, o2;
    o0.x = A*lw0.x + Bc*(v0 + pw0.x) + S*zw0.x;
    o0.y = A*lw0.y + Bc*(v1 + pw0.y) + S*zw0.y;
    o1.x = A*lw1.x + Bc*(v2 + pw1.x) + S*zw1.x;
    o1.y = A*lw1.y + Bc*(v3 + pw1.y) + S*zw1.y;
    o2.x = A*lw2.x + Bc*(v4 + pw2.x) + S*zw2.x;
    o2.y = A*lw2.y + Bc*(v5 + pw2.y) + S*zw2.y;

    float2* out2 = reinterpret_cast<float2*>(out + b6);
    out2[0] = o0;
    out2[1] = o1;
    out2[2] = o2;
}

extern "C" void kernel_launch(void* const* d_in, const int* in_sizes, int n_in,
                              void* d_out, int out_size, void* d_ws, size_t ws_size,
                              hipStream_t stream) {
    const float* lt         = (const float*)d_in[0];
    const float* pl0        = (const float*)d_in[1];
    const float* plat       = (const float*)d_in[2];
    const float* alpha_bars = (const float*)d_in[3];
    const float* betas      = (const float*)d_in[4];
    const float* sigmas     = (const float*)d_in[5];
    const float* z_noise    = (const float*)d_in[6];
    const int*   t          = (const int*)d_in[7];
    float* out = (float*)d_out;
    float* ws  = (float*)d_ws;

    int n = in_sizes[0] / 6;   // B rows
    int use_ws = (ws != nullptr && ws_size >= (size_t)(3 * TBL * sizeof(float)));

    if (use_ws) {
        sched_kernel<<<(TBL + 255) / 256, 256, 0, stream>>>(alpha_bars, betas, sigmas, ws);
    }
    int grid = (n + BLOCK - 1) / BLOCK;
    vp_lattice_kernel<<<grid, BLOCK, 0, stream>>>(
        lt, pl0, plat, alpha_bars, betas, sigmas, z_noise, t, out, n, ws, use_ws);
}